// Round 9
// baseline (1021.924 us; speedup 1.0000x reference)
//
#include <hip/hip_runtime.h>

#define N_NODES 45000
#define F_NNZ   33
#define NUM_STEPS 30
#define NPAIRS  (N_NODES / 2)        // 22500 row-pairs
#define REC     68                   // dwords per row-pair record
#define HCHUNK  100
#define NHEADBLK (N_NODES / HCHUNK)  // 450

__device__ inline float bf2f(unsigned short u) {
    return __uint_as_float(((unsigned int)u) << 16);
}
__device__ inline unsigned short f2bf(float f) {
    unsigned int x = __float_as_uint(f);
    unsigned int r = (x + 0x7fffu + ((x >> 16) & 1u)) >> 16;   // RNE
    return (unsigned short)r;
}

// Row-pair record rp: [33 dwords row 2rp][33 dwords row 2rp+1][bias 2rp][bias 2rp+1]
// each pk dword = (bf16(value) << 16) | u16(idx)
__global__ __launch_bounds__(256) void pack2_kernel(const int* __restrict__ idx,
                                                    const float* __restrict__ values,
                                                    const float* __restrict__ bias,
                                                    unsigned int* __restrict__ pk2) {
    int t = blockIdx.x * 256 + threadIdx.x;
    if (t >= NPAIRS * REC) return;
    int rp = t / REC, s = t % REC;
    unsigned int o;
    if (s < 33) {
        int n = rp * 2, f = s;
        o = (((unsigned int)f2bf(values[(size_t)n * F_NNZ + f])) << 16)
            | (unsigned int)idx[(size_t)n * F_NNZ + f];
    } else if (s < 66) {
        int n = rp * 2 + 1, f = s - 33;
        o = (((unsigned int)f2bf(values[(size_t)n * F_NNZ + f])) << 16)
            | (unsigned int)idx[(size_t)n * F_NNZ + f];
    } else {
        o = __float_as_uint(bias[rp * 2 + (s - 66)]);
    }
    pk2[t] = o;
}

// x (B=64, N) -> split transposed halves: xT{0,1} fp32 (N,32), g0{0,1} = bf16(2x)
__global__ __launch_bounds__(256) void transpose_init(const float* __restrict__ x,
                                                      float* __restrict__ xT0,
                                                      float* __restrict__ xT1,
                                                      unsigned short* __restrict__ g0,
                                                      unsigned short* __restrict__ g1) {
    __shared__ float tile[64][65];
    int n0  = blockIdx.x * 64;
    int t   = threadIdx.x;
    int ln  = t & 63;
    int sub = t >> 6;
    for (int bb = 0; bb < 16; ++bb) {
        int b = bb * 4 + sub;
        int n = n0 + ln;
        float v = (n < N_NODES) ? x[(size_t)b * N_NODES + n] : 0.f;
        tile[ln][b] = v;
    }
    __syncthreads();
    for (int nn = 0; nn < 16; ++nn) {
        int nrel = nn * 4 + sub;
        int n = n0 + nrel;
        if (n < N_NODES) {
            float v = tile[nrel][ln];         // ln = b
            int half = ln >> 5, l32 = ln & 31;
            size_t pos = (size_t)n * 32 + l32;
            (half ? xT1 : xT0)[pos] = v;
            (half ? g1 : g0)[pos] = f2bf(2.f * v);
        }
    }
}

// Persistent step: 2048 blocks (8/CU), XCD-pinned (XCDs 0-3 = half 0, 4-7 =
// half 1). gIn (2.88 MB/half) is the ONLY L2-allocating stream: pk2 record
// fetched per row-pair with ONE coalesced nt vector load + readlane extraction
// (no K$/L2 pollution); xT nt-load; gOut nt-store.
__global__ __launch_bounds__(256, 8) void step_kernel(const unsigned short* __restrict__ g0In,
                                                      const unsigned short* __restrict__ g1In,
                                                      const float* __restrict__ xT0,
                                                      const float* __restrict__ xT1,
                                                      const unsigned int* __restrict__ pk2,
                                                      unsigned short* __restrict__ g0Out,
                                                      unsigned short* __restrict__ g1Out,
                                                      int addX) {
    int b    = (int)blockIdx.x;
    int xcd  = b & 7;
    int half = xcd >> 2;
    int sub  = ((b >> 3) << 2) | (xcd & 3);   // 0..1023 within half
    int wid  = threadIdx.x >> 6;
    int lane = threadIdx.x & 63;
    int rowsel = lane >> 5;
    int l32    = lane & 31;

    const unsigned short* gIn  = half ? g1In  : g0In;
    const float*          xT   = half ? xT1   : xT0;
    unsigned short*       gOut = half ? g1Out : g0Out;

    int w = sub * 4 + wid;                    // wave id within half (0..4095)
    for (int rp = w; rp < NPAIRS; rp += 4096) {
        size_t base = (size_t)rp * REC;
        // one coalesced 256B nt load (lanes 0..63) + 16B tail (lanes re-read 64..67)
        unsigned int d  = __builtin_nontemporal_load(&pk2[base + lane]);
        unsigned int dx = __builtin_nontemporal_load(&pk2[base + 64 + (lane & 3)]);

        float acc = 0.f;
#pragma unroll
        for (int f = 0; f < F_NNZ; ++f) {
            // row0 entry f at dword f (<64); row1 entry f at dword 33+f
            unsigned int e0 = __builtin_amdgcn_readlane(d, f);
            unsigned int e1 = (33 + f < 64)
                                ? __builtin_amdgcn_readlane(d, 33 + f)
                                : __builtin_amdgcn_readlane(dx, 33 + f - 64);
            unsigned int e  = rowsel ? e1 : e0;
            int   j = (int)(e & 0xffffu);
            float v = __uint_as_float(e & 0xffff0000u);    // bf16 value in high bits
            acc = fmaf(v, bf2f(gIn[(size_t)j * 32 + l32]), acc);
        }
        float b0 = __uint_as_float(__builtin_amdgcn_readlane(dx, 2));
        float b1 = __uint_as_float(__builtin_amdgcn_readlane(dx, 3));
        int n = rp * 2 + rowsel;
        float tv = fmaxf(acc + (rowsel ? b1 : b0), 0.f);
        size_t o = (size_t)n * 32 + l32;
        float ov = tv;
        if (addX) ov += __builtin_nontemporal_load(&xT[o]);
        __builtin_nontemporal_store(f2bf(ov), &gOut[o]);
    }
}

// Head GEMM partials, no atomics. lane = b (coalesced h-row load), wave w owns
// h in [16w, 16w+16). Partial layout is [h][b] (h*64 + b).
__global__ __launch_bounds__(256) void head_partial4(const unsigned short* __restrict__ h0,
                                                     const unsigned short* __restrict__ h1,
                                                     const float* __restrict__ w1,
                                                     float* __restrict__ partial) {
    int lane = threadIdx.x & 63;   // b
    int w    = threadIdx.x >> 6;   // h-group
    const unsigned short* hh = (lane >> 5) ? h1 : h0;
    int l32  = lane & 31;
    int n0   = blockIdx.x * HCHUNK;
    float acc[16];
#pragma unroll
    for (int k = 0; k < 16; ++k) acc[k] = 0.f;
    for (int i = 0; i < HCHUNK; ++i) {
        int n = n0 + i;
        float hv = bf2f(hh[(size_t)n * 32 + l32]);           // coalesced
        const float* wrow = w1 + (size_t)n * 64 + w * 16;    // wave-uniform
#pragma unroll
        for (int k = 0; k < 16; ++k)
            acc[k] = fmaf(hv, wrow[k], acc[k]);
    }
    float* pp = partial + (size_t)blockIdx.x * 4096;
#pragma unroll
    for (int k = 0; k < 16; ++k)
        pp[(size_t)(w * 16 + k) * 64 + lane] = acc[k];       // [h][b]
}

// hidAcc[t] = sum over chunks of partial[chunk][t]  (layout [h][b] preserved)
__global__ __launch_bounds__(256) void head_reduce(const float* __restrict__ partial,
                                                   float* __restrict__ hidAcc) {
    int t = blockIdx.x * 256 + threadIdx.x;
    float acc = 0.f;
    for (int i = 0; i < NHEADBLK; ++i) acc += partial[(size_t)i * 4096 + t];
    hidAcc[t] = acc;
}

// out[b][c] = b2[c] + sum_h relu(hid[h][b] + b1[h]) * w2[h][c]   (hidAcc is [h][b])
__global__ __launch_bounds__(1024) void head_final(const float* __restrict__ hidAcc,
                                                   const float* __restrict__ b1,
                                                   const float* __restrict__ w2,
                                                   const float* __restrict__ b2,
                                                   float* __restrict__ out) {
    int t = threadIdx.x;
    if (t >= 640) return;
    int b = t / 10, c = t % 10;
    float acc = b2[c];
#pragma unroll
    for (int h = 0; h < 64; ++h) {
        float hv = fmaxf(hidAcc[h * 64 + b] + b1[h], 0.f);   // transposed read
        acc = fmaf(hv, w2[h * 10 + c], acc);
    }
    out[t] = acc;
}

extern "C" void kernel_launch(void* const* d_in, const int* in_sizes, int n_in,
                              void* d_out, int out_size, void* d_ws, size_t ws_size,
                              hipStream_t stream) {
    const float* x      = (const float*)d_in[0];
    const float* values = (const float*)d_in[1];
    const float* bias   = (const float*)d_in[2];
    const float* w1     = (const float*)d_in[3];
    const float* b1     = (const float*)d_in[4];
    const float* w2     = (const float*)d_in[5];
    const float* b2     = (const float*)d_in[6];
    const int*   idx    = (const int*)d_in[7];
    float* out = (float*)d_out;

    size_t perHalfF = (size_t)N_NODES * 32;
    float*          xT0 = (float*)d_ws;                        // 5.76 MB
    float*          xT1 = xT0 + perHalfF;                      // 5.76 MB
    unsigned short* gA0 = (unsigned short*)(xT1 + perHalfF);   // 2.88 MB each
    unsigned short* gB0 = gA0 + perHalfF;
    unsigned short* gA1 = gB0 + perHalfF;
    unsigned short* gB1 = gA1 + perHalfF;
    unsigned int*   pk2 = (unsigned int*)(gB1 + perHalfF);     // 6.12 MB (+pad)
    float*          partial = (float*)(pk2 + (size_t)NPAIRS * REC + 64);  // 7.37 MB
    float*          hidAcc  = partial + (size_t)NHEADBLK * 4096;          // 16 KB

    pack2_kernel<<<(NPAIRS * REC + 255) / 256, 256, 0, stream>>>(idx, values, bias, pk2);
    transpose_init<<<(N_NODES + 63) / 64, 256, 0, stream>>>(x, xT0, xT1, gA0, gA1);

    const unsigned short* gin0 = gA0; unsigned short* gout0 = gB0;
    const unsigned short* gin1 = gA1; unsigned short* gout1 = gB1;
    for (int s = 0; s < NUM_STEPS; ++s) {
        int addX = (s < NUM_STEPS - 1) ? 1 : 0;
        step_kernel<<<2048, 256, 0, stream>>>(gin0, gin1, xT0, xT1, pk2,
                                              gout0, gout1, addX);
        unsigned short* t0 = (unsigned short*)gin0; gin0 = gout0; gout0 = t0;
        unsigned short* t1 = (unsigned short*)gin1; gin1 = gout1; gout1 = t1;
    }

    head_partial4<<<NHEADBLK, 256, 0, stream>>>(gin0, gin1, w1, partial);
    head_reduce<<<16, 256, 0, stream>>>(partial, hidAcc);
    head_final<<<1, 1024, 0, stream>>>(hidAcc, b1, w2, b2, out);
}

// Round 10
// 701.824 us; speedup vs baseline: 1.4561x; 1.4561x over previous
//
#include <hip/hip_runtime.h>

#define N_NODES 45000
#define F_NNZ   33
#define NUM_STEPS 30
#define HCHUNK  100
#define NHEADBLK (N_NODES / HCHUNK)  // 450

__device__ inline float bf2f(unsigned short u) {
    return __uint_as_float(((unsigned int)u) << 16);
}
__device__ inline unsigned short f2bf(float f) {
    unsigned int x = __float_as_uint(f);
    unsigned int r = (x + 0x7fffu + ((x >> 16) & 1u)) >> 16;   // RNE
    return (unsigned short)r;
}

// pk[t] = (bf16(values[t]) << 16) | u16(idx[t])   — 4 B per nnz entry
__global__ __launch_bounds__(256) void pack_kernel(const int* __restrict__ idx,
                                                   const float* __restrict__ values,
                                                   unsigned int* __restrict__ pk) {
    int t = blockIdx.x * 256 + threadIdx.x;
    if (t >= N_NODES * F_NNZ) return;
    unsigned int vb = f2bf(values[t]);
    pk[t] = (vb << 16) | (unsigned int)idx[t];
}

// x (B=64, N) -> xT (N,64) fp32 and g0 (N,64) = bf16(2x)  (h0 = x)
__global__ __launch_bounds__(256) void transpose_init(const float* __restrict__ x,
                                                      float* __restrict__ xT,
                                                      unsigned short* __restrict__ g0) {
    __shared__ float tile[64][65];
    int n0  = blockIdx.x * 64;
    int t   = threadIdx.x;
    int ln  = t & 63;
    int sub = t >> 6;
    for (int bb = 0; bb < 16; ++bb) {
        int b = bb * 4 + sub;
        int n = n0 + ln;
        float v = (n < N_NODES) ? x[(size_t)b * N_NODES + n] : 0.f;
        tile[ln][b] = v;
    }
    __syncthreads();
    for (int nn = 0; nn < 16; ++nn) {
        int nrel = nn * 4 + sub;
        int n = n0 + nrel;
        if (n < N_NODES) {
            float v = tile[nrel][ln];          // ln = b
            size_t pos = (size_t)n * 64 + ln;
            xT[pos] = v;
            g0[pos] = f2bf(2.f * v);
        }
    }
}

// Persistent step, full-width g (N,64) bf16: each gather = ONE 128 B segment
// (64 lanes x 2 B contiguous) -> 1.485M requests/step (request-rate-bound).
// 2048 blocks (8/CU), wave = 1 row, grid-stride. pk row scalar-loaded
// (wave-uniform), xT nt-load, gOut nt-store.
__global__ __launch_bounds__(256, 8) void step_kernel(const unsigned short* __restrict__ gIn,
                                                      const float* __restrict__ xT,
                                                      const unsigned int* __restrict__ pk,
                                                      const float* __restrict__ bias,
                                                      unsigned short* __restrict__ gOut,
                                                      int addX) {
    int wid  = threadIdx.x >> 6;
    int lane = threadIdx.x & 63;     // b
    int w = (int)blockIdx.x * 4 + wid;        // 0..8191
    for (int n = w; n < N_NODES; n += 8192) {
        int nu = __builtin_amdgcn_readfirstlane(n);
        const unsigned int* p = pk + (size_t)nu * F_NNZ;
        float acc = 0.f;
#pragma unroll
        for (int f = 0; f < F_NNZ; ++f) {
            unsigned int e = p[f];                         // scalar load
            int   j = (int)(e & 0xffffu);
            float v = __uint_as_float(e & 0xffff0000u);    // bf16 value in hi bits
            acc = fmaf(v, bf2f(gIn[(size_t)j * 64 + lane]), acc);
        }
        float tv = fmaxf(acc + bias[nu], 0.f);
        size_t o = (size_t)nu * 64 + lane;
        float ov = tv;
        if (addX) ov += __builtin_nontemporal_load(&xT[o]);
        __builtin_nontemporal_store(f2bf(ov), &gOut[o]);
    }
}

// Head GEMM partials. lane = b (coalesced 128 B h-row load), wave w owns
// h in [16w, 16w+16). Partial layout [h][b] (h*64 + b).
__global__ __launch_bounds__(256) void head_partial4(const unsigned short* __restrict__ h,
                                                     const float* __restrict__ w1,
                                                     float* __restrict__ partial) {
    int lane = threadIdx.x & 63;   // b
    int w    = threadIdx.x >> 6;   // h-group
    int n0   = blockIdx.x * HCHUNK;
    float acc[16];
#pragma unroll
    for (int k = 0; k < 16; ++k) acc[k] = 0.f;
    for (int i = 0; i < HCHUNK; ++i) {
        int n = n0 + i;
        float hv = bf2f(h[(size_t)n * 64 + lane]);           // coalesced
        const float* wrow = w1 + (size_t)n * 64 + w * 16;    // wave-uniform
#pragma unroll
        for (int k = 0; k < 16; ++k)
            acc[k] = fmaf(hv, wrow[k], acc[k]);
    }
    float* pp = partial + (size_t)blockIdx.x * 4096;
#pragma unroll
    for (int k = 0; k < 16; ++k)
        pp[(size_t)(w * 16 + k) * 64 + lane] = acc[k];       // [h][b]
}

// hidAcc[t] = sum over chunks of partial[chunk][t]  (layout [h][b] preserved)
__global__ __launch_bounds__(256) void head_reduce(const float* __restrict__ partial,
                                                   float* __restrict__ hidAcc) {
    int t = blockIdx.x * 256 + threadIdx.x;
    float acc = 0.f;
    for (int i = 0; i < NHEADBLK; ++i) acc += partial[(size_t)i * 4096 + t];
    hidAcc[t] = acc;
}

// out[b][c] = b2[c] + sum_h relu(hid[h][b] + b1[h]) * w2[h][c]   (hidAcc is [h][b])
__global__ __launch_bounds__(1024) void head_final(const float* __restrict__ hidAcc,
                                                   const float* __restrict__ b1,
                                                   const float* __restrict__ w2,
                                                   const float* __restrict__ b2,
                                                   float* __restrict__ out) {
    int t = threadIdx.x;
    if (t >= 640) return;
    int b = t / 10, c = t % 10;
    float acc = b2[c];
#pragma unroll
    for (int h = 0; h < 64; ++h) {
        float hv = fmaxf(hidAcc[h * 64 + b] + b1[h], 0.f);   // transposed read
        acc = fmaf(hv, w2[h * 10 + c], acc);
    }
    out[t] = acc;
}

extern "C" void kernel_launch(void* const* d_in, const int* in_sizes, int n_in,
                              void* d_out, int out_size, void* d_ws, size_t ws_size,
                              hipStream_t stream) {
    const float* x      = (const float*)d_in[0];
    const float* values = (const float*)d_in[1];
    const float* bias   = (const float*)d_in[2];
    const float* w1     = (const float*)d_in[3];
    const float* b1     = (const float*)d_in[4];
    const float* w2     = (const float*)d_in[5];
    const float* b2     = (const float*)d_in[6];
    const int*   idx    = (const int*)d_in[7];
    float* out = (float*)d_out;

    size_t per = (size_t)N_NODES * 64;
    float*          xT  = (float*)d_ws;                        // 11.5 MB
    unsigned short* gA  = (unsigned short*)(xT + per);         // 5.76 MB
    unsigned short* gB  = gA + per;                            // 5.76 MB
    unsigned int*   pk  = (unsigned int*)(gB + per);           // 5.94 MB
    float*          partial = (float*)(pk + (size_t)N_NODES * F_NNZ);  // 7.37 MB
    float*          hidAcc  = partial + (size_t)NHEADBLK * 4096;       // 16 KB

    pack_kernel<<<(N_NODES * F_NNZ + 255) / 256, 256, 0, stream>>>(idx, values, pk);
    transpose_init<<<(N_NODES + 63) / 64, 256, 0, stream>>>(x, xT, gA);

    const unsigned short* gin = gA;
    unsigned short*       gout = gB;
    for (int s = 0; s < NUM_STEPS; ++s) {
        int addX = (s < NUM_STEPS - 1) ? 1 : 0;
        step_kernel<<<2048, 256, 0, stream>>>(gin, xT, pk, bias, gout, addX);
        unsigned short* t0 = (unsigned short*)gin; gin = gout; gout = t0;
    }

    head_partial4<<<NHEADBLK, 256, 0, stream>>>(gin, w1, partial);
    head_reduce<<<16, 256, 0, stream>>>(partial, hidAcc);
    head_final<<<1, 1024, 0, stream>>>(hidAcc, b1, w2, b2, out);
}